// Round 1
// baseline (2051.825 us; speedup 1.0000x reference)
//
#include <hip/hip_runtime.h>
#include <math.h>

// Problem constants
#define NB    64
#define D     256
#define K     1024
#define HW    1024          // 32*32 spatial positions per batch
#define NTOT  65536         // NB*HW rows
#define MARGIN 1e-4f        // fp32-phase ambiguity margin (phase-1 err ~1e-6)

// Output layout (floats): [0]=loss, [1..16777216]=quantized NCHW,
// [16777217]=perplexity, [16777218..+67108864)=encodings, then quantized_flat
#define OUT_QOUT   1
#define OUT_PERP   16777217
#define OUT_ENC    16777218
#define OUT_QFLAT  83886082

// ws layout (bytes): 0 double lossAcc; 8 int rescueCount; 16 int hist[1024];
// 4112 float enorm[1024]; 8208 int idx[65536]; 270352 int rlist[65536]  (~520KB)

__global__ void enorm_kernel(const float* __restrict__ emb, float* __restrict__ enorm) {
    int k = blockIdx.x * 256 + threadIdx.x;
    const float4* row = (const float4*)(emb + (size_t)k * D);
    float s = 0.f;
    #pragma unroll
    for (int q = 0; q < D / 4; q++) {
        float4 v = row[q];
        s += v.x * v.x + v.y * v.y + v.z * v.z + v.w * v.w;
    }
    enorm[k] = s;
}

// ---- Phase 1: fp32 scores s_k = |e_k|^2 - 2 f.e_k, per-row (min1, idx, min2) ----
#define BM 32
#define BN 512
#define DC 16

__global__ __launch_bounds__(256, 2) void score_argmin_kernel(
    const float* __restrict__ in, const float* __restrict__ emb,
    const float* __restrict__ enorm, int* __restrict__ idx,
    int* __restrict__ rcount, int* __restrict__ rlist)
{
    __shared__ float sF[D * BM];   // [d][p]  word = d*32 + p   (32 KB)
    __shared__ float sE[DC * BN];  // [dd][kk] word = dd*512+kk (32 KB)

    const int t = threadIdx.x;
    const int n0 = blockIdx.x * BM;
    const int b = n0 >> 10, p0 = n0 & 1023;
    const float* inB = in + (size_t)b * (D * HW) + p0;

    // Load f-tile: thread t owns d=t, 32 consecutive p (one/two cache lines, reused)
    {
        const float4* src = (const float4*)(inB + (size_t)t * HW);
        float4* dst = (float4*)(sF + t * BM);
        #pragma unroll
        for (int q = 0; q < BM / 4; q++) dst[q] = src[q];
    }

    const int w = t >> 6;      // wave id -> row group (8 rows)
    const int lane = t & 63;   // k group (8 ks)

    float m1[8], m2[8]; int i1[8];
    #pragma unroll
    for (int i = 0; i < 8; i++) { m1[i] = 3.4e38f; m2[i] = 3.4e38f; i1[i] = 0; }

    for (int kt = 0; kt < K / BN; kt++) {
        const int k0 = kt * BN;
        float acc[8][8];
        #pragma unroll
        for (int i = 0; i < 8; i++)
            #pragma unroll
            for (int j = 0; j < 8; j++) acc[i][j] = 0.f;

        for (int c = 0; c < D / DC; c++) {
            const int d0 = c * DC;
            __syncthreads();   // also guards sF initial load on first pass
            // stage e-tile transposed: sE[dd][kk]
            #pragma unroll
            for (int h = 0; h < 2; h++) {
                const int kk = t + h * 256;
                const float4* er = (const float4*)(emb + (size_t)(k0 + kk) * D + d0);
                #pragma unroll
                for (int q = 0; q < 4; q++) {
                    float4 v = er[q];
                    sE[(q * 4 + 0) * BN + kk] = v.x;
                    sE[(q * 4 + 1) * BN + kk] = v.y;
                    sE[(q * 4 + 2) * BN + kk] = v.z;
                    sE[(q * 4 + 3) * BN + kk] = v.w;
                }
            }
            __syncthreads();
            #pragma unroll
            for (int dd = 0; dd < DC; dd++) {
                const float4* aF = (const float4*)(sF + (d0 + dd) * BM + w * 8);
                float4 a0 = aF[0], a1 = aF[1];                       // wave-uniform (broadcast)
                const float4* bF = (const float4*)(sE + dd * BN + lane * 8);
                float4 b0 = bF[0], b1 = bF[1];
                float av[8] = {a0.x, a0.y, a0.z, a0.w, a1.x, a1.y, a1.z, a1.w};
                float bv[8] = {b0.x, b0.y, b0.z, b0.w, b1.x, b1.y, b1.z, b1.w};
                #pragma unroll
                for (int i = 0; i < 8; i++)
                    #pragma unroll
                    for (int j = 0; j < 8; j++)
                        acc[i][j] = fmaf(av[i], bv[j], acc[i][j]);
            }
        }
        // epilogue: scores + running min1/min2
        const float4* enr = (const float4*)(enorm + k0 + lane * 8);
        float4 e0 = enr[0], e1 = enr[1];
        float en[8] = {e0.x, e0.y, e0.z, e0.w, e1.x, e1.y, e1.z, e1.w};
        #pragma unroll
        for (int j = 0; j < 8; j++) {
            const int kg = k0 + lane * 8 + j;
            #pragma unroll
            for (int i = 0; i < 8; i++) {
                float s = en[j] - 2.f * acc[i][j];
                if (s < m1[i]) { m2[i] = m1[i]; m1[i] = s; i1[i] = kg; }
                else if (s < m2[i]) m2[i] = s;
            }
        }
    }

    // per-row reduce across the 64 lanes of this wave (rows w*8+i)
    #pragma unroll
    for (int i = 0; i < 8; i++) {
        float a1v = m1[i], a2v = m2[i]; int ai = i1[i];
        #pragma unroll
        for (int off = 32; off >= 1; off >>= 1) {
            float o1 = __shfl_xor(a1v, off, 64);
            int   oi = __shfl_xor(ai,  off, 64);
            float o2 = __shfl_xor(a2v, off, 64);
            float n2 = fminf(fminf(a2v, o2), fmaxf(a1v, o1));
            if (o1 < a1v || (o1 == a1v && oi < ai)) { a1v = o1; ai = oi; }
            a2v = n2;
        }
        if (lane == 0) {
            const int n = n0 + w * 8 + i;
            idx[n] = ai;
            if (a2v - a1v < MARGIN) {
                int pos = atomicAdd(rcount, 1);
                rlist[pos] = n;
            }
        }
    }
}

// ---- Phase 2: fp64 re-score of ambiguous rows (true argmin, lowest-idx ties) ----
__global__ void rescue_kernel(const float* __restrict__ in, const float* __restrict__ emb,
                              const int* __restrict__ rcount, const int* __restrict__ rlist,
                              int* __restrict__ idx)
{
    const int wid = blockIdx.x * 4 + (threadIdx.x >> 6);
    const int lane = threadIdx.x & 63;
    const int count = *rcount;
    for (int li = wid; li < count; li += 256 * 4) {
        const int n = rlist[li];
        const int b = n >> 10, p = n & 1023;
        const float* f = in + (size_t)b * (D * HW) + p;
        float fr[4];
        #pragma unroll
        for (int q = 0; q < 4; q++) fr[q] = f[(size_t)(lane + q * 64) * HW];
        double bm = 1e300; int bk = 0;
        for (int kk = 0; kk < 16; kk++) {
            const int k = lane + kk * 64;
            const float* er = emb + (size_t)k * D;
            double s = 0.0;
            #pragma unroll
            for (int q = 0; q < 4; q++) {
                for (int dl = 0; dl < 64; dl++) {
                    double fv = (double)__shfl(fr[q], dl, 64);
                    double ev = (double)er[q * 64 + dl];
                    s += ev * (ev - 2.0 * fv);   // |e|^2 - 2 f.e, fused
                }
            }
            if (s < bm || (s == bm && k < bk)) { bm = s; bk = k; }
        }
        #pragma unroll
        for (int off = 32; off >= 1; off >>= 1) {
            double om = __shfl_xor(bm, off, 64);
            int    ok = __shfl_xor(bk, off, 64);
            if (om < bm || (om == bm && ok < bk)) { bm = om; bk = ok; }
        }
        if (lane == 0) idx[n] = bk;
    }
}

// ---- Outputs ----
__global__ __launch_bounds__(256) void qout_loss_kernel(
    const float* __restrict__ in, const float* __restrict__ emb,
    const int* __restrict__ idx, float* __restrict__ out, double* __restrict__ lossAcc)
{
    const int o = blockIdx.x * 256 + threadIdx.x;       // NCHW linear index
    const int b = o >> 18, rem = o & 262143;
    const int d = rem >> 10, p = rem & 1023;
    const int n = (b << 10) | p;
    const int k = idx[n];
    const float q = emb[k * D + d];
    const float x = in[o];
    out[OUT_QOUT + o] = q;                               // ST value == q to ~6e-7
    const float df = q - x;
    double v = (double)df * (double)df;
    #pragma unroll
    for (int off = 32; off >= 1; off >>= 1) v += __shfl_xor(v, off, 64);
    __shared__ double sred[4];
    if ((threadIdx.x & 63) == 0) sred[threadIdx.x >> 6] = v;
    __syncthreads();
    if (threadIdx.x == 0) atomicAdd(lossAcc, sred[0] + sred[1] + sred[2] + sred[3]);
}

__global__ void qflat_kernel(const float* __restrict__ emb, const int* __restrict__ idx,
                             float* __restrict__ outQF)
{
    const int i = blockIdx.x * 256 + threadIdx.x;       // float2 index
    const int o = i * 2;
    const int n = o >> 8;
    const int d = o & 255;
    const int k = idx[n];
    const float2 v = *(const float2*)(emb + k * D + d);
    *(float2*)(outQF + o) = v;
}

__global__ void scatter_hist_kernel(const int* __restrict__ idx, float* __restrict__ outEnc,
                                    int* __restrict__ hist)
{
    const int n = blockIdx.x * 256 + threadIdx.x;
    const int k = idx[n];
    outEnc[(size_t)n * K + k] = 1.0f;
    atomicAdd(&hist[k], 1);
}

__global__ void finalize_kernel(const int* __restrict__ hist, const double* __restrict__ lossAcc,
                                float* __restrict__ out)
{
    const int t = threadIdx.x;
    double s = 0.0;
    #pragma unroll
    for (int q = 0; q < 4; q++) {
        const int c = hist[t + q * 256];
        const double p = (double)c / (double)NTOT;
        s += p * log(p + 1e-10);
    }
    #pragma unroll
    for (int off = 32; off >= 1; off >>= 1) s += __shfl_xor(s, off, 64);
    __shared__ double sr[4];
    if ((t & 63) == 0) sr[t >> 6] = s;
    __syncthreads();
    if (t == 0) {
        out[0] = (float)(1.25 * (*lossAcc) / (double)(NTOT * (size_t)D));
        out[OUT_PERP] = (float)exp(-(sr[0] + sr[1] + sr[2] + sr[3]));
    }
}

extern "C" void kernel_launch(void* const* d_in, const int* in_sizes, int n_in,
                              void* d_out, int out_size, void* d_ws, size_t ws_size,
                              hipStream_t stream)
{
    const float* in  = (const float*)d_in[0];   // [64,256,32,32] fp32
    const float* emb = (const float*)d_in[1];   // [1024,256] fp32
    float* out = (float*)d_out;
    char* ws = (char*)d_ws;

    double* lossAcc = (double*)(ws + 0);
    int*    rcount  = (int*)(ws + 8);
    int*    hist    = (int*)(ws + 16);
    float*  enorm   = (float*)(ws + 4112);
    int*    idx     = (int*)(ws + 8208);
    int*    rlist   = (int*)(ws + 270352);

    // zero loss/count/hist (ws is poisoned 0xAA each call); zero encodings region
    hipMemsetAsync(ws, 0, 8208, stream);
    hipMemsetAsync(out + OUT_ENC, 0, (size_t)NTOT * K * sizeof(float), stream);

    enorm_kernel<<<K / 256, 256, 0, stream>>>(emb, enorm);
    score_argmin_kernel<<<NTOT / BM, 256, 0, stream>>>(in, emb, enorm, idx, rcount, rlist);
    rescue_kernel<<<256, 256, 0, stream>>>(in, emb, rcount, rlist, idx);
    qout_loss_kernel<<<(NB * D * HW) / 256, 256, 0, stream>>>(in, emb, idx, out, lossAcc);
    qflat_kernel<<<(NTOT * D / 2) / 256, 256, 0, stream>>>(emb, idx, out + OUT_QFLAT);
    scatter_hist_kernel<<<NTOT / 256 / 256 * 256, 256, 0, stream>>>(idx, out + OUT_ENC, hist);
    finalize_kernel<<<1, 256, 0, stream>>>(hist, lossAcc, out);
}

// Round 2
// 1310.630 us; speedup vs baseline: 1.5655x; 1.5655x over previous
//
#include <hip/hip_runtime.h>
#include <math.h>

// Problem constants
#define NB    64
#define D     256
#define K     1024
#define HW    1024          // 32*32 spatial positions per batch
#define NTOT  65536         // NB*HW rows
#define MARGIN 1e-4f        // fp32-phase ambiguity margin (phase-1 err ~1e-6)

// Output layout (floats): [0]=loss, [1..16777216]=quantized NCHW,
// [16777217]=perplexity, [16777218..+67108864)=encodings, then quantized_flat
#define OUT_QOUT   1
#define OUT_PERP   16777217
#define OUT_ENC    16777218
#define OUT_QFLAT  83886082

#define LOSS_BLOCKS 1024

// ws layout (bytes):
//   0      int rescueCount
//   16     int hist[1024]
//   4112   float enorm[1024]
//   8208   int idx[65536]
//   270352 int rlist[65536]
//   532496 double lossPartial[LOSS_BLOCKS]   (8KB)
//   total ~541KB

__global__ void enorm_kernel(const float* __restrict__ emb, float* __restrict__ enorm) {
    int k = blockIdx.x * 256 + threadIdx.x;
    const float4* row = (const float4*)(emb + (size_t)k * D);
    float s = 0.f;
    #pragma unroll
    for (int q = 0; q < D / 4; q++) {
        float4 v = row[q];
        s += v.x * v.x + v.y * v.y + v.z * v.z + v.w * v.w;
    }
    enorm[k] = s;
}

// ---- Phase 1: fp32 scores s_k = |e_k|^2 - 2 f.e_k, per-row (min1, idx, min2) ----
#define BM 32
#define BN 512
#define DC 16

__global__ __launch_bounds__(256, 2) void score_argmin_kernel(
    const float* __restrict__ in, const float* __restrict__ emb,
    const float* __restrict__ enorm, int* __restrict__ idx,
    int* __restrict__ rcount, int* __restrict__ rlist)
{
    __shared__ float sF[D * BM];   // [d][p]  word = d*32 + p   (32 KB)
    __shared__ float sE[DC * BN];  // [dd][kk] word = dd*512+kk (32 KB)

    const int t = threadIdx.x;
    const int n0 = blockIdx.x * BM;
    const int b = n0 >> 10, p0 = n0 & 1023;
    const float* inB = in + (size_t)b * (D * HW) + p0;

    // Load f-tile: thread t owns d=t, 32 consecutive p (one/two cache lines, reused)
    {
        const float4* src = (const float4*)(inB + (size_t)t * HW);
        float4* dst = (float4*)(sF + t * BM);
        #pragma unroll
        for (int q = 0; q < BM / 4; q++) dst[q] = src[q];
    }

    const int w = t >> 6;      // wave id -> row group (8 rows)
    const int lane = t & 63;   // k group (8 ks)

    float m1[8], m2[8]; int i1[8];
    #pragma unroll
    for (int i = 0; i < 8; i++) { m1[i] = 3.4e38f; m2[i] = 3.4e38f; i1[i] = 0; }

    for (int kt = 0; kt < K / BN; kt++) {
        const int k0 = kt * BN;
        float acc[8][8];
        #pragma unroll
        for (int i = 0; i < 8; i++)
            #pragma unroll
            for (int j = 0; j < 8; j++) acc[i][j] = 0.f;

        for (int c = 0; c < D / DC; c++) {
            const int d0 = c * DC;
            __syncthreads();   // also guards sF initial load on first pass
            // stage e-tile transposed: sE[dd][kk]
            #pragma unroll
            for (int h = 0; h < 2; h++) {
                const int kk = t + h * 256;
                const float4* er = (const float4*)(emb + (size_t)(k0 + kk) * D + d0);
                #pragma unroll
                for (int q = 0; q < 4; q++) {
                    float4 v = er[q];
                    sE[(q * 4 + 0) * BN + kk] = v.x;
                    sE[(q * 4 + 1) * BN + kk] = v.y;
                    sE[(q * 4 + 2) * BN + kk] = v.z;
                    sE[(q * 4 + 3) * BN + kk] = v.w;
                }
            }
            __syncthreads();
            #pragma unroll
            for (int dd = 0; dd < DC; dd++) {
                const float4* aF = (const float4*)(sF + (d0 + dd) * BM + w * 8);
                float4 a0 = aF[0], a1 = aF[1];                       // wave-uniform (broadcast)
                const float4* bF = (const float4*)(sE + dd * BN + lane * 8);
                float4 b0 = bF[0], b1 = bF[1];
                float av[8] = {a0.x, a0.y, a0.z, a0.w, a1.x, a1.y, a1.z, a1.w};
                float bv[8] = {b0.x, b0.y, b0.z, b0.w, b1.x, b1.y, b1.z, b1.w};
                #pragma unroll
                for (int i = 0; i < 8; i++)
                    #pragma unroll
                    for (int j = 0; j < 8; j++)
                        acc[i][j] = fmaf(av[i], bv[j], acc[i][j]);
            }
        }
        // epilogue: scores + running min1/min2
        const float4* enr = (const float4*)(enorm + k0 + lane * 8);
        float4 e0 = enr[0], e1 = enr[1];
        float en[8] = {e0.x, e0.y, e0.z, e0.w, e1.x, e1.y, e1.z, e1.w};
        #pragma unroll
        for (int j = 0; j < 8; j++) {
            const int kg = k0 + lane * 8 + j;
            #pragma unroll
            for (int i = 0; i < 8; i++) {
                float s = en[j] - 2.f * acc[i][j];
                if (s < m1[i]) { m2[i] = m1[i]; m1[i] = s; i1[i] = kg; }
                else if (s < m2[i]) m2[i] = s;
            }
        }
    }

    // per-row reduce across the 64 lanes of this wave (rows w*8+i)
    #pragma unroll
    for (int i = 0; i < 8; i++) {
        float a1v = m1[i], a2v = m2[i]; int ai = i1[i];
        #pragma unroll
        for (int off = 32; off >= 1; off >>= 1) {
            float o1 = __shfl_xor(a1v, off, 64);
            int   oi = __shfl_xor(ai,  off, 64);
            float o2 = __shfl_xor(a2v, off, 64);
            float n2 = fminf(fminf(a2v, o2), fmaxf(a1v, o1));
            if (o1 < a1v || (o1 == a1v && oi < ai)) { a1v = o1; ai = oi; }
            a2v = n2;
        }
        if (lane == 0) {
            const int n = n0 + w * 8 + i;
            idx[n] = ai;
            if (a2v - a1v < MARGIN) {
                int pos = atomicAdd(rcount, 1);
                rlist[pos] = n;
            }
        }
    }
}

// ---- Phase 2: fp64 re-score of ambiguous rows (true argmin, lowest-idx ties) ----
__global__ void rescue_kernel(const float* __restrict__ in, const float* __restrict__ emb,
                              const int* __restrict__ rcount, const int* __restrict__ rlist,
                              int* __restrict__ idx)
{
    const int wid = blockIdx.x * 4 + (threadIdx.x >> 6);
    const int lane = threadIdx.x & 63;
    const int count = *rcount;
    for (int li = wid; li < count; li += 256 * 4) {
        const int n = rlist[li];
        const int b = n >> 10, p = n & 1023;
        const float* f = in + (size_t)b * (D * HW) + p;
        float fr[4];
        #pragma unroll
        for (int q = 0; q < 4; q++) fr[q] = f[(size_t)(lane + q * 64) * HW];
        double bm = 1e300; int bk = 0;
        for (int kk = 0; kk < 16; kk++) {
            const int k = lane + kk * 64;
            const float* er = emb + (size_t)k * D;
            double s = 0.0;
            #pragma unroll
            for (int q = 0; q < 4; q++) {
                for (int dl = 0; dl < 64; dl++) {
                    double fv = (double)__shfl(fr[q], dl, 64);
                    double ev = (double)er[q * 64 + dl];
                    s += ev * (ev - 2.0 * fv);   // |e|^2 - 2 f.e, fused
                }
            }
            if (s < bm || (s == bm && k < bk)) { bm = s; bk = k; }
        }
        #pragma unroll
        for (int off = 32; off >= 1; off >>= 1) {
            double om = __shfl_xor(bm, off, 64);
            int    ok = __shfl_xor(bk, off, 64);
            if (om < bm || (om == bm && ok < bk)) { bm = om; bk = ok; }
        }
        if (lane == 0) idx[n] = bk;
    }
}

// ---- Outputs ----
// Grid-stride, float4-vectorized, NO global atomics: per-block partial into ws.
__global__ __launch_bounds__(256) void qout_loss_kernel(
    const float* __restrict__ in, const float* __restrict__ emb,
    const int* __restrict__ idx, float* __restrict__ out, double* __restrict__ partial)
{
    const int NQ4 = NB * D * HW / 4;
    double acc = 0.0;
    for (int i4 = blockIdx.x * 256 + threadIdx.x; i4 < NQ4; i4 += LOSS_BLOCKS * 256) {
        const int o = i4 * 4;
        const int b = o >> 18, rem = o & 262143;
        const int d = rem >> 10, p = rem & 1023;     // p..p+3 stay in-row (o%4==0)
        const int n = (b << 10) | p;
        const int4 kv = *(const int4*)(idx + n);     // coalesced
        const float4 x = *(const float4*)(in + o);
        float4 q;
        q.x = emb[kv.x * D + d];
        q.y = emb[kv.y * D + d];
        q.z = emb[kv.z * D + d];
        q.w = emb[kv.w * D + d];
        *(float4*)(out + OUT_QOUT + o) = q;          // ST value == q to ~6e-7
        const float dx = q.x - x.x, dy = q.y - x.y, dz = q.z - x.z, dw = q.w - x.w;
        acc += (double)(dx * dx + dy * dy) + (double)(dz * dz + dw * dw);
    }
    #pragma unroll
    for (int off = 32; off >= 1; off >>= 1) acc += __shfl_xor(acc, off, 64);
    __shared__ double sred[4];
    if ((threadIdx.x & 63) == 0) sred[threadIdx.x >> 6] = acc;
    __syncthreads();
    if (threadIdx.x == 0) partial[blockIdx.x] = sred[0] + sred[1] + sred[2] + sred[3];
}

__global__ void qflat_kernel(const float* __restrict__ emb, const int* __restrict__ idx,
                             float* __restrict__ outQF)
{
    const int i = blockIdx.x * 256 + threadIdx.x;       // float2 index
    const int o = i * 2;
    const int n = o >> 8;
    const int d = o & 255;
    const int k = idx[n];
    const float2 v = *(const float2*)(emb + k * D + d);
    *(float2*)(outQF + o) = v;
}

__global__ void scatter_hist_kernel(const int* __restrict__ idx, float* __restrict__ outEnc,
                                    int* __restrict__ hist)
{
    const int n = blockIdx.x * 256 + threadIdx.x;
    const int k = idx[n];
    outEnc[(size_t)n * K + k] = 1.0f;
    atomicAdd(&hist[k], 1);
}

__global__ void finalize_kernel(const int* __restrict__ hist, const double* __restrict__ lossPartial,
                                float* __restrict__ out)
{
    const int t = threadIdx.x;
    // perplexity
    double s = 0.0;
    #pragma unroll
    for (int q = 0; q < 4; q++) {
        const int c = hist[t + q * 256];
        const double p = (double)c / (double)NTOT;
        s += p * log(p + 1e-10);
    }
    // loss partial sum
    double l = 0.0;
    #pragma unroll
    for (int q = 0; q < LOSS_BLOCKS / 256; q++) l += lossPartial[t + q * 256];
    #pragma unroll
    for (int off = 32; off >= 1; off >>= 1) {
        s += __shfl_xor(s, off, 64);
        l += __shfl_xor(l, off, 64);
    }
    __shared__ double sr[4], lr[4];
    if ((t & 63) == 0) { sr[t >> 6] = s; lr[t >> 6] = l; }
    __syncthreads();
    if (t == 0) {
        out[0] = (float)(1.25 * (lr[0] + lr[1] + lr[2] + lr[3]) / (double)(NTOT * (size_t)D));
        out[OUT_PERP] = (float)exp(-(sr[0] + sr[1] + sr[2] + sr[3]));
    }
}

extern "C" void kernel_launch(void* const* d_in, const int* in_sizes, int n_in,
                              void* d_out, int out_size, void* d_ws, size_t ws_size,
                              hipStream_t stream)
{
    const float* in  = (const float*)d_in[0];   // [64,256,32,32] fp32
    const float* emb = (const float*)d_in[1];   // [1024,256] fp32
    float* out = (float*)d_out;
    char* ws = (char*)d_ws;

    int*    rcount  = (int*)(ws + 0);
    int*    hist    = (int*)(ws + 16);
    float*  enorm   = (float*)(ws + 4112);
    int*    idx     = (int*)(ws + 8208);
    int*    rlist   = (int*)(ws + 270352);
    double* lossPartial = (double*)(ws + 532496);

    // zero count/hist (ws is poisoned 0xAA each call); zero encodings region
    hipMemsetAsync(ws, 0, 8208, stream);
    hipMemsetAsync(out + OUT_ENC, 0, (size_t)NTOT * K * sizeof(float), stream);

    enorm_kernel<<<K / 256, 256, 0, stream>>>(emb, enorm);
    score_argmin_kernel<<<NTOT / BM, 256, 0, stream>>>(in, emb, enorm, idx, rcount, rlist);
    rescue_kernel<<<256, 256, 0, stream>>>(in, emb, rcount, rlist, idx);
    qout_loss_kernel<<<LOSS_BLOCKS, 256, 0, stream>>>(in, emb, idx, out, lossPartial);
    qflat_kernel<<<(NTOT * D / 2) / 256, 256, 0, stream>>>(emb, idx, out + OUT_QFLAT);
    scatter_hist_kernel<<<NTOT / 256, 256, 0, stream>>>(idx, out + OUT_ENC, hist);
    finalize_kernel<<<1, 256, 0, stream>>>(hist, lossPartial, out);
}

// Round 3
// 1244.049 us; speedup vs baseline: 1.6493x; 1.0535x over previous
//
#include <hip/hip_runtime.h>
#include <hip/hip_bf16.h>
#include <math.h>

// Problem constants
#define NB    64
#define D     256
#define K     1024
#define HW    1024
#define NTOT  65536
#define MARGIN 1e-4f   // phase-1 (bf16x3 MFMA) score error ~1.5e-7 << margin

// Output layout (floats)
#define OUT_QOUT   1
#define OUT_PERP   16777217
#define OUT_ENC    16777218
#define OUT_QFLAT  83886082

// ws layout (bytes):
//   0      int rcount
//   16     int hist[1024]
//   4112   float enorm[1024]
//   8208   int idx[65536]            -> 270352
//   270352 int rlist[65536]          -> 532496
//   532496 double lossPartial[2048]  -> 548880
//   548880 ushort efrag[524288]      -> 1597456   (bf16 fragment-layout E, hi+lo)
// efrag layout: [h(2)][ntg(64)][dc(8)][lane(64)][j(8)] bf16
//   element = split_h( emb[ k = ntg*16 + (lane&15) ][ d = dc*32 + (lane>>4)*8 + j ] )

typedef __attribute__((ext_vector_type(8))) short bf16x8;
typedef __attribute__((ext_vector_type(4))) float f32x4;

__global__ void enorm_kernel(const float* __restrict__ emb, float* __restrict__ enorm) {
    int k = blockIdx.x * 256 + threadIdx.x;
    const float4* row = (const float4*)(emb + (size_t)k * D);
    float s = 0.f;
    #pragma unroll
    for (int q = 0; q < D / 4; q++) {
        float4 v = row[q];
        s += v.x * v.x + v.y * v.y + v.z * v.z + v.w * v.w;
    }
    enorm[k] = s;
}

// ---- Pre-split E into MFMA B-fragment layout (hi/lo bf16), once ----
__global__ void esplit_kernel(const float* __restrict__ emb, ushort* __restrict__ efrag) {
    const int ntg = blockIdx.x;          // 64 blocks: one 16-col k-tile each
    const int t = threadIdx.x;
    __shared__ float sEm[16 * 260];      // 16 rows x 256 d, pad 4

    // stage emb rows k = ntg*16 .. +15
    {
        const int row = t >> 4, seg = t & 15;
        const float4* src = (const float4*)(emb + (size_t)(ntg * 16 + row) * D + seg * 16);
        float4* dst = (float4*)(sEm + row * 260 + seg * 16);
        #pragma unroll
        for (int q = 0; q < 4; q++) dst[q] = src[q];
    }
    __syncthreads();

    const int w = t >> 6, lane = t & 63;
    for (int fb = w; fb < 16; fb += 4) {         // fb = h*8 + dc
        const int h = fb >> 3, dc = fb & 7;
        const float* srcp = sEm + (lane & 15) * 260 + dc * 32 + (lane >> 4) * 8;
        ushort o[8];
        #pragma unroll
        for (int j = 0; j < 8; j++) {
            float x = srcp[j];
            __hip_bfloat16 hb = __float2bfloat16(x);
            if (h == 0) { o[j] = *(ushort*)&hb; }
            else {
                float hf = __bfloat162float(hb);
                __hip_bfloat16 lb = __float2bfloat16(x - hf);
                o[j] = *(ushort*)&lb;
            }
        }
        ushort* dst = efrag + ((size_t)(h * 64 + ntg) * 8 + dc) * 512 + lane * 8;
        *(int4*)dst = *(int4*)o;
    }
}

// ---- Phase 1: MFMA bf16x3 scores + in-kernel argmin (min1, idx, min2) ----
// Block: 64 rows x full K=1024 (4 k-passes of 256). 4 waves; each wave: all 4 m-tiles x 4 n-tiles.
__global__ __launch_bounds__(256, 2) void score_mfma_kernel(
    const float* __restrict__ in, const ushort* __restrict__ efrag,
    const float* __restrict__ enorm, int* __restrict__ idx,
    int* __restrict__ rcount, int* __restrict__ rlist)
{
    __shared__ ushort sA[32768];   // [h(2)][mt(4)][dc(8)][lane(64)][j(8)] bf16 = 64KB

    const int t = threadIdx.x;
    const int n0 = blockIdx.x * 64;
    const int b = n0 >> 10, p0 = n0 & 1023;

    // Stage A: thread t owns d=t, all 64 rows; convert to hi/lo, write fragment layout.
    {
        const float* src = in + (size_t)b * (D * HW) + (size_t)t * HW + p0;
        const int quad = (t >> 3) & 3, dc = t >> 5, j = t & 7;
        #pragma unroll
        for (int g = 0; g < 4; g++) {                  // mt = g
            float xs[16];
            #pragma unroll
            for (int q = 0; q < 4; q++) {
                float4 v = ((const float4*)src)[g * 4 + q];
                xs[q * 4 + 0] = v.x; xs[q * 4 + 1] = v.y; xs[q * 4 + 2] = v.z; xs[q * 4 + 3] = v.w;
            }
            #pragma unroll
            for (int mm = 0; mm < 16; mm++) {
                float x = xs[mm];
                __hip_bfloat16 hb = __float2bfloat16(x);
                float hf = __bfloat162float(hb);
                __hip_bfloat16 lb = __float2bfloat16(x - hf);
                const int l = mm + 16 * quad;
                sA[((0 * 4 + g) * 8 + dc) * 512 + l * 8 + j] = *(ushort*)&hb;
                sA[((1 * 4 + g) * 8 + dc) * 512 + l * 8 + j] = *(ushort*)&lb;
            }
        }
    }
    __syncthreads();

    const int w = t >> 6, lane = t & 63;

    float rm1[16], rm2[16]; int ri[16];   // running per (mt*4+r); rows = mt*16 + (lane>>4)*4 + r
    #pragma unroll
    for (int q = 0; q < 16; q++) { rm1[q] = 3.4e38f; rm2[q] = 3.4e38f; ri[q] = 0; }

    for (int kp = 0; kp < 4; kp++) {
        float env[4]; int kc[4];
        #pragma unroll
        for (int ntl = 0; ntl < 4; ntl++) {
            kc[ntl] = kp * 256 + (w * 4 + ntl) * 16 + (lane & 15);
            env[ntl] = enorm[kc[ntl]];
        }
        f32x4 acc[4][4];
        #pragma unroll
        for (int mt = 0; mt < 4; mt++)
            #pragma unroll
            for (int ntl = 0; ntl < 4; ntl++) acc[mt][ntl] = (f32x4){0.f, 0.f, 0.f, 0.f};

        // B frags from L2-resident global, prefetched one dc ahead
        bf16x8 bh[4], bl[4], nbh[4], nbl[4];
        {
            #pragma unroll
            for (int ntl = 0; ntl < 4; ntl++) {
                const int ntg = kp * 16 + w * 4 + ntl;
                const size_t off = ((size_t)ntg * 8 + 0) * 512 + lane * 8;
                bh[ntl] = *(const bf16x8*)(efrag + off);
                bl[ntl] = *(const bf16x8*)(efrag + off + 262144);
            }
        }
        for (int dc = 0; dc < 8; dc++) {
            if (dc < 7) {
                #pragma unroll
                for (int ntl = 0; ntl < 4; ntl++) {
                    const int ntg = kp * 16 + w * 4 + ntl;
                    const size_t off = ((size_t)ntg * 8 + dc + 1) * 512 + lane * 8;
                    nbh[ntl] = *(const bf16x8*)(efrag + off);
                    nbl[ntl] = *(const bf16x8*)(efrag + off + 262144);
                }
            }
            #pragma unroll
            for (int mt = 0; mt < 4; mt++) {
                bf16x8 ah = *(const bf16x8*)(sA + ((0 * 4 + mt) * 8 + dc) * 512 + lane * 8);
                bf16x8 al = *(const bf16x8*)(sA + ((1 * 4 + mt) * 8 + dc) * 512 + lane * 8);
                #pragma unroll
                for (int ntl = 0; ntl < 4; ntl++) {
                    acc[mt][ntl] = __builtin_amdgcn_mfma_f32_16x16x32_bf16(al, bh[ntl], acc[mt][ntl], 0, 0, 0);
                    acc[mt][ntl] = __builtin_amdgcn_mfma_f32_16x16x32_bf16(ah, bl[ntl], acc[mt][ntl], 0, 0, 0);
                    acc[mt][ntl] = __builtin_amdgcn_mfma_f32_16x16x32_bf16(ah, bh[ntl], acc[mt][ntl], 0, 0, 0);
                }
            }
            if (dc < 7) {
                #pragma unroll
                for (int ntl = 0; ntl < 4; ntl++) { bh[ntl] = nbh[ntl]; bl[ntl] = nbl[ntl]; }
            }
        }

        // epilogue: scores + per-row reduce (16 lanes per quad hold 16 k-cols of one row)
        #pragma unroll
        for (int mt = 0; mt < 4; mt++)
            #pragma unroll
            for (int r = 0; r < 4; r++) {
                float m1 = 3.4e38f, m2 = 3.4e38f; int i1 = 0;
                #pragma unroll
                for (int ntl = 0; ntl < 4; ntl++) {
                    float s = env[ntl] - 2.0f * acc[mt][ntl][r];
                    if (s < m1) { m2 = m1; m1 = s; i1 = kc[ntl]; }
                    else if (s < m2) m2 = s;
                }
                #pragma unroll
                for (int mask = 1; mask <= 8; mask <<= 1) {
                    float o1 = __shfl_xor(m1, mask, 64);
                    int   oi = __shfl_xor(i1, mask, 64);
                    float o2 = __shfl_xor(m2, mask, 64);
                    float n2 = fminf(fminf(m2, o2), fmaxf(m1, o1));
                    if (o1 < m1 || (o1 == m1 && oi < i1)) { m1 = o1; i1 = oi; }
                    m2 = n2;
                }
                const int q = mt * 4 + r;
                float n2 = fminf(fminf(rm2[q], m2), fmaxf(rm1[q], m1));
                if (m1 < rm1[q] || (m1 == rm1[q] && i1 < ri[q])) { rm1[q] = m1; ri[q] = i1; }
                rm2[q] = n2;
            }
    }

    // cross-wave merge via LDS (alias sA; all MFMA A-reads done)
    __syncthreads();
    float* sM1 = (float*)sA;           // [4][64]
    float* sM2 = sM1 + 256;
    int*   sI  = (int*)(sM2 + 256);
    #pragma unroll
    for (int mt = 0; mt < 4; mt++)
        #pragma unroll
        for (int r = 0; r < 4; r++) {
            if ((lane & 15) == 0) {
                const int row = mt * 16 + (lane >> 4) * 4 + r;
                sM1[w * 64 + row] = rm1[mt * 4 + r];
                sM2[w * 64 + row] = rm2[mt * 4 + r];
                sI [w * 64 + row] = ri [mt * 4 + r];
            }
        }
    __syncthreads();
    if (t < 64) {
        float b1 = sM1[t], b2 = sM2[t]; int bi = sI[t];
        #pragma unroll
        for (int ww = 1; ww < 4; ww++) {
            float a1 = sM1[ww * 64 + t], a2 = sM2[ww * 64 + t]; int ai = sI[ww * 64 + t];
            float n2 = fminf(fminf(b2, a2), fmaxf(b1, a1));
            if (a1 < b1 || (a1 == b1 && ai < bi)) { b1 = a1; bi = ai; }
            b2 = n2;
        }
        const int n = n0 + t;
        idx[n] = bi;
        if (b2 - b1 < MARGIN) {
            int pos = atomicAdd(rcount, 1);
            rlist[pos] = n;
        }
    }
}

// ---- Phase 2: fp64 re-score of ambiguous rows (true argmin, lowest-idx ties) ----
__global__ void rescue_kernel(const float* __restrict__ in, const float* __restrict__ emb,
                              const int* __restrict__ rcount, const int* __restrict__ rlist,
                              int* __restrict__ idx)
{
    const int wid = blockIdx.x * 4 + (threadIdx.x >> 6);
    const int lane = threadIdx.x & 63;
    const int count = *rcount;
    for (int li = wid; li < count; li += 256 * 4) {
        const int n = rlist[li];
        const int b = n >> 10, p = n & 1023;
        const float* f = in + (size_t)b * (D * HW) + p;
        float fr[4];
        #pragma unroll
        for (int q = 0; q < 4; q++) fr[q] = f[(size_t)(lane + q * 64) * HW];
        double bm = 1e300; int bk = 0;
        for (int kk = 0; kk < 16; kk++) {
            const int k = lane + kk * 64;
            const float* er = emb + (size_t)k * D;
            double s = 0.0;
            #pragma unroll
            for (int q = 0; q < 4; q++) {
                for (int dl = 0; dl < 64; dl++) {
                    double fv = (double)__shfl(fr[q], dl, 64);
                    double ev = (double)er[q * 64 + dl];
                    s += ev * (ev - 2.0 * fv);
                }
            }
            if (s < bm || (s == bm && k < bk)) { bm = s; bk = k; }
        }
        #pragma unroll
        for (int off = 32; off >= 1; off >>= 1) {
            double om = __shfl_xor(bm, off, 64);
            int    ok = __shfl_xor(bk, off, 64);
            if (om < bm || (om == bm && ok < bk)) { bm = om; bk = ok; }
        }
        if (lane == 0) idx[n] = bk;
    }
}

// ---- Fused outputs: qout(NCHW) + loss partials + qflat + one-hot + hist ----
// Block = 32 rows x 256 d, emb rows staged in LDS (coalesced gather).
__global__ __launch_bounds__(256) void outputs_kernel(
    const float* __restrict__ in, const float* __restrict__ emb,
    const int* __restrict__ idx, float* __restrict__ out,
    double* __restrict__ lossPartial, int* __restrict__ hist)
{
    __shared__ int skv[32];
    __shared__ float sQ[32 * 260];
    __shared__ double sred[4];

    const int t = threadIdx.x;
    const int n0 = blockIdx.x * 32;
    const int b = n0 >> 10, p0 = n0 & 1023;

    if (t < 32) skv[t] = idx[n0 + t];
    __syncthreads();

    // stage emb rows (coalesced per 8-thread group) + write qflat directly
    {
        const int r = t >> 3, c0 = (t & 7) * 32;
        const int kv = skv[r];
        const float4* src = (const float4*)(emb + (size_t)kv * D + c0);
        float4* dstL = (float4*)(sQ + r * 260 + c0);
        float4* dstG = (float4*)(out + OUT_QFLAT + (size_t)(n0 + r) * D + c0);
        #pragma unroll
        for (int g = 0; g < 8; g++) {
            float4 v = src[g];
            dstL[g] = v;
            dstG[g] = v;
        }
    }
    if (t < 32) {
        const int kv = skv[t];
        out[OUT_ENC + (size_t)(n0 + t) * K + kv] = 1.0f;
        atomicAdd(&hist[kv], 1);
    }
    __syncthreads();

    // qout NCHW + loss: lanes cover p (coalesced 128B per 32-lane group)
    const int p = t & 31, dg = t >> 5;
    double acc = 0.0;
    const size_t obase = (size_t)b * (D * HW) + p0 + p;
    #pragma unroll
    for (int dd = 0; dd < 32; dd++) {
        const int d = dg * 32 + dd;
        const float q = sQ[p * 260 + d];
        const float x = in[obase + (size_t)d * HW];
        out[OUT_QOUT + obase + (size_t)d * HW] = q;
        const float df = q - x;
        acc += (double)(df * df);
    }
    #pragma unroll
    for (int off = 32; off >= 1; off >>= 1) acc += __shfl_xor(acc, off, 64);
    if ((t & 63) == 0) sred[t >> 6] = acc;
    __syncthreads();
    if (t == 0) lossPartial[blockIdx.x] = sred[0] + sred[1] + sred[2] + sred[3];
}

__global__ void finalize_kernel(const int* __restrict__ hist, const double* __restrict__ lossPartial,
                                float* __restrict__ out)
{
    const int t = threadIdx.x;
    double s = 0.0;
    #pragma unroll
    for (int q = 0; q < 4; q++) {
        const int c = hist[t + q * 256];
        const double p = (double)c / (double)NTOT;
        s += p * log(p + 1e-10);
    }
    double l = 0.0;
    #pragma unroll
    for (int q = 0; q < 8; q++) l += lossPartial[t + q * 256];
    #pragma unroll
    for (int off = 32; off >= 1; off >>= 1) {
        s += __shfl_xor(s, off, 64);
        l += __shfl_xor(l, off, 64);
    }
    __shared__ double sr[4], lr[4];
    if ((t & 63) == 0) { sr[t >> 6] = s; lr[t >> 6] = l; }
    __syncthreads();
    if (t == 0) {
        out[0] = (float)(1.25 * (lr[0] + lr[1] + lr[2] + lr[3]) / (double)(NTOT * (size_t)D));
        out[OUT_PERP] = (float)exp(-(sr[0] + sr[1] + sr[2] + sr[3]));
    }
}

extern "C" void kernel_launch(void* const* d_in, const int* in_sizes, int n_in,
                              void* d_out, int out_size, void* d_ws, size_t ws_size,
                              hipStream_t stream)
{
    const float* in  = (const float*)d_in[0];   // [64,256,32,32] fp32
    const float* emb = (const float*)d_in[1];   // [1024,256] fp32
    float* out = (float*)d_out;
    char* ws = (char*)d_ws;

    int*    rcount      = (int*)(ws + 0);
    int*    hist        = (int*)(ws + 16);
    float*  enorm       = (float*)(ws + 4112);
    int*    idx         = (int*)(ws + 8208);
    int*    rlist       = (int*)(ws + 270352);
    double* lossPartial = (double*)(ws + 532496);
    ushort* efrag       = (ushort*)(ws + 548880);

    hipMemsetAsync(ws, 0, 8208, stream);                                   // rcount + hist
    hipMemsetAsync(out + OUT_ENC, 0, (size_t)NTOT * K * sizeof(float), stream);

    enorm_kernel<<<K / 256, 256, 0, stream>>>(emb, enorm);
    esplit_kernel<<<K / 16, 256, 0, stream>>>(emb, efrag);
    score_mfma_kernel<<<NTOT / 64, 256, 0, stream>>>(in, efrag, enorm, idx, rcount, rlist);
    rescue_kernel<<<256, 256, 0, stream>>>(in, emb, rcount, rlist, idx);
    outputs_kernel<<<NTOT / 32, 256, 0, stream>>>(in, emb, idx, out, lossPartial, hist);
    finalize_kernel<<<1, 256, 0, stream>>>(hist, lossPartial, out);
}